// Round 1
// baseline (282.900 us; speedup 1.0000x reference)
//
#include <hip/hip_runtime.h>
#include <math.h>

#ifndef M_PI
#define M_PI 3.14159265358979323846
#endif

#define Hh   256
#define Ww   1216
#define HWsz (Hh * Ww)          // 311296
#define Bb   32
#define KH   30
#define KW   49
#define NTAP (KH * KW)          // 1470
#define SHs  16
#define SWs  48
#define NPB  (SHs * SWs)        // 768 points per batch
#define NPTS (Bb * NPB)         // 24576
#define OUT0 (Bb * HWsz)        // 9961472
#define OUT1 (Bb * HWsz * 2)    // 19922944

// Bilinear tap matching reference gather(): mask on float coords, clip-then-trunc index.
__device__ __forceinline__ float samp4(const float* __restrict__ g, float yc, float xc, float w) {
#pragma clang fp contract(off)
    bool m = (yc >= 0.0f) && (yc <= 255.0f) && (xc >= 0.0f) && (xc <= 1215.0f);
    float ycl = fminf(fmaxf(yc, 0.0f), 255.0f);
    float xcl = fminf(fmaxf(xc, 0.0f), 1215.0f);
    int yi = (int)ycl, xi = (int)xcl;
    float wm = m ? w : 0.0f;
    return g[yi * Ww + xi] * wm;
}

// One wave per (batch, i, j) sample point: 30x49 Gaussian window dot-product on both
// channels (fp64 accumulate, fp32 weights identical to numpy's cast), then grid add,
// bilinear gather from gt, and scatter-coordinate computation.
__global__ __launch_bounds__(256) void k_conv_sample(
    const float* __restrict__ gt, const float* __restrict__ dvf,
    float* __restrict__ out2, float* __restrict__ vbuf, int* __restrict__ rcbuf)
{
#pragma clang fp contract(off)
    __shared__ double s_gh[KH];
    __shared__ double s_gw[KW];
    __shared__ double s_S;
    __shared__ float  s_w[NTAP];
    const int tid = threadIdx.x;

    if (tid < KH) {
        const double sh_ = (2.0 * 256.0 / 17.0) / 3.0;     // mirrors 2*H/(SH+1)/3.0
        double u = ((double)tid - 14.5) / sh_;             // (kh-1)/2 = 14.5
        s_gh[tid] = exp(-(u * u) / 2.0) / (sh_ * sqrt(2.0 * M_PI));
    } else if (tid >= 64 && tid < 64 + KW) {
        int t = tid - 64;
        const double sw_ = (2.0 * 1216.0 / 49.0) / 3.0;
        double u = ((double)t - 24.0) / sw_;               // (kw-1)/2 = 24.0
        s_gw[t] = exp(-(u * u) / 2.0) / (sw_ * sqrt(2.0 * M_PI));
    }
    __syncthreads();
    if (tid == 0) {
        double a = 0.0, c = 0.0;
        for (int t = 0; t < KH; ++t) a += s_gh[t];
        for (int t = 0; t < KW; ++t) c += s_gw[t];
        s_S = a * c;                                       // == k.sum() up to 1e-16
    }
    __syncthreads();
    for (int t = tid; t < NTAP; t += 256)
        s_w[t] = (float)((s_gh[t / KW] * s_gw[t % KW]) / s_S);  // fp64 -> fp32 cast like numpy
    __syncthreads();

    const int wave = tid >> 6, lane = tid & 63;
    const int pt = blockIdx.x * 4 + wave;                  // grid sized exactly: pt < NPTS
    const int b = pt / NPB, p = pt - b * NPB;
    const int i = p / SWs, j = p - i * SWs;
    const int y0r = (i * 227) >> 4;                        // arange(16)*227//16
    const int x0c = (j * 1168) / 48;                       // arange(48)*1168//48
    const float* c0 = dvf + (size_t)b * (2 * HWsz) + y0r * Ww + x0c;
    const float* c1 = c0 + HWsz;

    double a0 = 0.0, a1 = 0.0;
    for (int t = lane; t < NTAP; t += 64) {
        int dy = t / KW, dx = t - dy * KW;
        int off = dy * Ww + dx;
        double w = (double)s_w[t];
        a0 += w * (double)c0[off];
        a1 += w * (double)c1[off];
    }
    for (int o = 32; o > 0; o >>= 1) {
        a0 += __shfl_down(a0, o);
        a1 += __shfl_down(a1, o);
    }

    if (lane == 0) {
        float sx = (float)a0, sy = (float)a1;              // smoothed (fp32, like ref conv out)
        // numpy linspace semantics: y = j*step + start, endpoint forced to stop.
        const double startw = -(47.0 / 48.0), stopw = 47.0 / 48.0;
        const double starth = -(15.0 / 16.0), stoph = 15.0 / 16.0;
        const double stepw = (stopw - startw) / 47.0;
        const double steph = (stoph - starth) / 15.0;
        float gwl = (j == SWs - 1) ? (float)stopw : (float)((double)j * stepw + startw);
        float ghl = (i == SHs - 1) ? (float)stoph : (float)((double)i * steph + starth);
        float gx = sx + gwl;
        float gy = sy + ghl;

        float* o2 = out2 + ((size_t)(b * SHs + i) * SWs + j) * 2;
        o2[0] = gx; o2[1] = gy;

        // bilinear: x = (gx+1)*W/2 - 0.5 with reference op order
        const float* gtb = gt + (size_t)b * HWsz;
        float xw = (gx + 1.0f) * 1216.0f; xw = xw / 2.0f; xw = xw - 0.5f;
        float yw = (gy + 1.0f) * 256.0f;  yw = yw / 2.0f; yw = yw - 0.5f;
        float x0f = floorf(xw), y0f = floorf(yw);
        float x1f = x0f + 1.0f, y1f = y0f + 1.0f;
        float wx1 = xw - x0f, wx0 = 1.0f - wx1;
        float wy1 = yw - y0f, wy0 = 1.0f - wy1;
        float v = samp4(gtb, y0f, x0f, wy0 * wx0) + samp4(gtb, y0f, x1f, wy0 * wx1)
                + samp4(gtb, y1f, x0f, wy1 * wx0) + samp4(gtb, y1f, x1f, wy1 * wx1);

        // scatter coords: trunc toward zero (astype(int32)) THEN clip
        float rf = (gy + 1.0f) / 2.0f * 256.0f;
        float cf = (gx + 1.0f) / 2.0f * 1216.0f;
        int row = (int)rf; row = row < 0 ? 0 : (row > Hh - 1 ? Hh - 1 : row);
        int col = (int)cf; col = col < 0 ? 0 : (col > Ww - 1 ? Ww - 1 : col);
        vbuf[pt]  = v;
        rcbuf[pt] = (row << 16) | col;
    }
}

// Per-batch serial replay so "last write wins" matches numpy row-major assignment order.
// Rows < 96 skipped (reference zeroes them after the scatter).
__global__ __launch_bounds__(256) void k_scatter(
    const float* __restrict__ vbuf, const int* __restrict__ rcbuf, float* __restrict__ out0)
{
    __shared__ float sv[NPB];
    __shared__ int   sr[NPB];
    const int b = blockIdx.x, tid = threadIdx.x;
    for (int t = tid; t < NPB; t += 256) {
        sv[t] = vbuf[b * NPB + t];
        sr[t] = rcbuf[b * NPB + t];
    }
    __syncthreads();
    if (tid == 0) {
        float* o = out0 + (size_t)b * HWsz;
        for (int p = 0; p < NPB; ++p) {
            int rc = sr[p];
            int r = rc >> 16, c = rc & 0xffff;
            if (r >= 96) o[r * Ww + c] = sv[p];
        }
    }
}

// NCHW [B,2,H,W] -> NHWC [B,H,W,2], 4 pixels (32B out) per thread.
__global__ __launch_bounds__(256) void k_transpose(
    const float* __restrict__ dvf, float* __restrict__ out1)
{
    const size_t idx = (size_t)blockIdx.x * 256 + threadIdx.x;   // over Bb * HWsz/4
    const int b = (int)(idx / (HWsz / 4));
    const int r = (int)(idx - (size_t)b * (HWsz / 4));
    const float4* p0 = (const float4*)(dvf + (size_t)b * 2 * HWsz);
    const float4* p1 = (const float4*)(dvf + (size_t)b * 2 * HWsz + HWsz);
    float4 a = p0[r], c = p1[r];
    float4* o = (float4*)(out1 + ((size_t)b * HWsz + (size_t)r * 4) * 2);
    o[0] = make_float4(a.x, c.x, a.y, c.y);
    o[1] = make_float4(a.z, c.z, a.w, c.w);
}

extern "C" void kernel_launch(void* const* d_in, const int* in_sizes, int n_in,
                              void* d_out, int out_size, void* d_ws, size_t ws_size,
                              hipStream_t stream) {
    const float* gt  = (const float*)d_in[0];
    const float* dvf = (const float*)d_in[1];
    float* out0 = (float*)d_out;
    float* out1 = out0 + OUT0;
    float* out2 = out1 + OUT1;
    float* vbuf  = (float*)d_ws;          // NPTS floats
    int*   rcbuf = (int*)d_ws + NPTS;     // NPTS ints (total 192 KiB of ws)

    hipMemsetAsync(d_out, 0, (size_t)OUT0 * sizeof(float), stream);
    hipLaunchKernelGGL(k_conv_sample, dim3(NPTS / 4), dim3(256), 0, stream,
                       gt, dvf, out2, vbuf, rcbuf);
    hipLaunchKernelGGL(k_transpose, dim3((Bb * (HWsz / 4)) / 256), dim3(256), 0, stream,
                       dvf, out1);
    hipLaunchKernelGGL(k_scatter, dim3(Bb), dim3(256), 0, stream,
                       vbuf, rcbuf, out0);
}